// Round 11
// baseline (238.463 us; speedup 1.0000x reference)
//
#include <hip/hip_runtime.h>
#include <math.h>

// ---------------------------------------------------------------------------
// Model: conv1(5x5,20)+pool2 -> conv2(5x5,50)+pool2 -> pcaps(5x5 pad2,16)
//        -> squash -> priors -> dynamic routing(3) -> fc1(relu) -> fc2
// B=2048. conv1/conv2/pcaps/fc1 via bf16 MFMA (16x16x32).
// k_fc1: 64x32 tile, BK=64, grid (32,16)=512 (2 blocks/CU so one block's
// barrier/vmcnt-drain overlaps the other's compute - m114 mechanism).
// h_bf POSITION-MAJOR: k' = pos*50 + oc, padded to 3648.
// ---------------------------------------------------------------------------

#define BATCH 2048
#define KP 3648          // padded K for fc1 (57 * 64)

typedef __attribute__((ext_vector_type(8))) short short8;
typedef __attribute__((ext_vector_type(4))) float floatx4;
typedef unsigned short u16;
typedef unsigned int   u32;

__device__ inline float wave_sum(float v) {
#pragma unroll
    for (int off = 32; off >= 1; off >>= 1) v += __shfl_xor(v, off);
    return v;
}
__device__ inline float wave_max(float v) {
#pragma unroll
    for (int off = 32; off >= 1; off >>= 1) v = fmaxf(v, __shfl_xor(v, off));
    return v;
}
__device__ inline u16 f2bf(float f) {  // RNE fp32->bf16 (finite)
    u32 u = __float_as_uint(f);
    u32 r = (u + 0x7FFFu + ((u >> 16) & 1u)) >> 16;
    return (u16)r;
}

// ---------- Kernel 0: weight conversions + out init ------------------------
__global__ __launch_bounds__(256) void k_prep(
    const float* __restrict__ fw,  u16* __restrict__ w_bf,
    const float* __restrict__ w2,  u16* __restrict__ w2t,
    const float* __restrict__ pcw, u16* __restrict__ w_pc,
    const float* __restrict__ w1,  u16* __restrict__ w1t,
    const float* __restrict__ y,   const float* __restrict__ f2w,
    const float* __restrict__ f2b, float* __restrict__ out)
{
    __shared__ __align__(16) float srow[3600];
    const int blk = blockIdx.x, t = threadIdx.x;
    if (blk < 500) {
        const int n = blk;
        const float* src = fw + (size_t)n * 3602;
        for (int i = t; i < 1800; i += 256)
            *(float2*)&srow[2 * i] = *(const float2*)&src[2 * i];
        __syncthreads();
        u32* dst = (u32*)(w_bf + (size_t)n * KP);
        for (int i = t; i < 1824; i += 256) {
            int k2 = 2 * i;
            u32 pk = 0u;
            if (k2 < 3600) {
                int pos = k2 / 50, oc = k2 - 50 * pos;
                pk = (u32)f2bf(srow[oc * 72 + pos])
                   | ((u32)f2bf(srow[(oc + 1) * 72 + pos]) << 16);
            }
            dst[i] = pk;
        }
    } else if (blk == 500) {
        u32* z = (u32*)(w_bf + (size_t)500 * KP);
        for (int i = t; i < 21888; i += 256) z[i] = 0u;   // 12 * 1824
    } else if (blk < 526) {
        int g   = (blk - 501) * 256 + t;
        int idx = g * 8;
        int tap = idx >> 11;
        int oc  = (idx >> 5) & 63;
        int ic0 = idx & 31;
        u16 v[8];
#pragma unroll
        for (int j = 0; j < 8; ++j) {
            int ic = ic0 + j;
            float f = (ic < 20 && oc < 50) ? w2[oc * 500 + ic * 25 + tap] : 0.f;
            v[j] = f2bf(f);
        }
        *(short8*)&w2t[idx] = *(short8*)v;
    } else if (blk < 539) {
        int g = (blk - 526) * 256 + t;
        if (g >= 3200) return;
        int idx = g * 8;
        int tap = idx >> 10;
        int rem = idx & 1023;
        int oc  = rem >> 6;
        int ic0 = rem & 63;
        u16 v[8];
#pragma unroll
        for (int j = 0; j < 8; ++j) {
            int ic = ic0 + j;
            float f = (ic < 50) ? pcw[(oc * 50 + ic) * 25 + tap] : 0.f;
            v[j] = f2bf(f);
        }
        *(short8*)&w_pc[idx] = *(short8*)v;
    } else if (blk == 539) {
        if (t < 128) {
            int n  = t >> 2;
            int k0 = (t & 3) * 8;
            u16 v[8];
#pragma unroll
            for (int j = 0; j < 8; ++j) {
                int k = k0 + j;
                float f = (n < 20 && k < 25) ? w1[n * 25 + k] : 0.f;
                v[j] = f2bf(f);
            }
            *(short8*)&w1t[t * 8] = *(short8*)v;
        }
    } else {
        int b = (blk - 540) * 256 + t;   // 0..2047
        float y0 = y[b * 2], y1 = y[b * 2 + 1];
        float2 o;
        o.x = f2b[0] + y0 * f2w[500] + y1 * f2w[501];
        o.y = f2b[1] + y0 * f2w[502 + 500] + y1 * f2w[502 + 501];
        *(float2*)&out[b * 2] = o;
    }
}

// ---------- Kernel 1: conv1+conv2 (MFMA) + pcaps (MFMA) + routing ----------
// LDS (49408 B union):
//   conv phase : h1t[448][40] u16 | xbf[36][64] u16 | im2[112][40] u16
//   pcaps phase: hs2 f32[3600] @0 | hsbuf u16[176][72] @14400 B
//                psum f32[4][80*17] (pitch 17 breaks 4/32-way banks) overlays
//                hsbuf | pri f32[576] @39744 B
__global__ __launch_bounds__(256, 3) void k_convs(
    const float* __restrict__ x, const u16* __restrict__ w1t,
    const float* __restrict__ b1, const u16* __restrict__ w2t,
    const float* __restrict__ b2, const u16* __restrict__ w_pc,
    const float* __restrict__ pcb, const float* __restrict__ rw,
    u32* __restrict__ h_bf, float* __restrict__ cbuf)
{
    __shared__ __align__(16) u16 smem[24704];
    u16* h1t = smem;            // 17920 shorts
    u16* xbf = smem + 17920;    // 2304 shorts
    u16* im2 = smem + 20224;    // 4480 shorts

    const int t = threadIdx.x;
    const int b = blockIdx.x;

    // zero the ic pad [20,32) of h1t rows; stage x as bf16
    for (int i = t; i < 2688; i += 256) {
        int pos = i / 6, c = i - 6 * pos;
        ((u32*)h1t)[pos * 20 + 10 + c] = 0u;
    }
    const float* xb = x + b * 2160;
    for (int i = t; i < 2160; i += 256) {
        int r = i / 60, c = i - 60 * r;
        xbf[r * 64 + c] = f2bf(xb[i]);
    }
    __syncthreads();

    const int lane = t & 63, w = t >> 6;
    const int r16  = lane & 15;
    const int q    = lane >> 4;

    // ---- conv1 via MFMA, 16 chunks of 2 pre-pool rows (112 positions) ----
    short8 w1f[2];
#pragma unroll
    for (int nt = 0; nt < 2; ++nt)
        w1f[nt] = *(const short8*)&w1t[(nt * 16 + r16) * 32 + q * 8];

    const int p_   = t;               // builder position (t<112)
    const int px_  = p_ >> 2;
    const int dy_  = (p_ & 3) >> 1, dx_ = p_ & 1;
    const int xc_  = 2 * px_ + dx_;
    const int j0_  = xc_ >> 1;
    const int par_ = xc_ & 1;

#pragma unroll 1
    for (int c = 0; c < 16; ++c) {
        if (t < 112) {
            u16 tap[25];
#pragma unroll
            for (int r = 0; r < 5; ++r) {
                const u32* U = (const u32*)&xbf[(2 * c + dy_ + r) * 64];
                u32 A0 = U[j0_], A1 = U[j0_ + 1], A2 = U[j0_ + 2];
                u16 e0 = par_ ? (u16)(A0 >> 16) : (u16)A0;
                u16 e1 = par_ ? (u16)A1         : (u16)(A0 >> 16);
                u16 e2 = par_ ? (u16)(A1 >> 16) : (u16)A1;
                u16 e3 = par_ ? (u16)A2         : (u16)(A1 >> 16);
                u16 e4 = par_ ? (u16)(A2 >> 16) : (u16)A2;
                tap[r * 5 + 0] = e0; tap[r * 5 + 1] = e1; tap[r * 5 + 2] = e2;
                tap[r * 5 + 3] = e3; tap[r * 5 + 4] = e4;
            }
            u32 ow[16];
#pragma unroll
            for (int j = 0; j < 12; ++j)
                ow[j] = (u32)tap[2 * j] | ((u32)tap[2 * j + 1] << 16);
            ow[12] = (u32)tap[24];
            ow[13] = 0u; ow[14] = 0u; ow[15] = 0u;
            u32* dst = (u32*)&im2[p_ * 40];
            *(uint4*)&dst[0]  = make_uint4(ow[0],  ow[1],  ow[2],  ow[3]);
            *(uint4*)&dst[4]  = make_uint4(ow[4],  ow[5],  ow[6],  ow[7]);
            *(uint4*)&dst[8]  = make_uint4(ow[8],  ow[9],  ow[10], ow[11]);
            *(uint4*)&dst[12] = make_uint4(ow[12], ow[13], ow[14], ow[15]);
        }
        __syncthreads();
#pragma unroll
        for (int mi = 0; mi < 2; ++mi) {
            int mt = w + 4 * mi;
            if (mt < 7) {
                short8 af = *(const short8*)&im2[(mt * 16 + r16) * 40 + q * 8];
                floatx4 a1[2] = {};
#pragma unroll
                for (int nt = 0; nt < 2; ++nt)
                    a1[nt] = __builtin_amdgcn_mfma_f32_16x16x32_bf16(
                        af, w1f[nt], a1[nt], 0, 0, 0);
                int pq = mt * 4 + q;
#pragma unroll
                for (int nt = 0; nt < 2; ++nt) {
                    int oc = nt * 16 + r16;
                    if (oc < 20) {
                        floatx4 a = a1[nt];
                        float v = fmaxf(fmaxf(a[0], a[1]), fmaxf(a[2], a[3]))
                                + b1[oc];
                        h1t[(c * 28 + pq) * 40 + oc] = f2bf(v);
                    }
                }
            }
        }
        __syncthreads();
    }

    // ---- conv2 via MFMA: M=288 Z-ordered pre-pool, N=64, K=32, 25 taps ----
    int abase[5];
#pragma unroll
    for (int i = 0; i < 5; ++i) {
        int mt = w + 4 * i;
        if (mt < 18) {
            int m  = mt * 16 + r16;
            int pq = m >> 2, sub = m & 3;
            int py = pq / 12, px = pq - py * 12;
            int yy = py * 2 + (sub >> 1);
            int xx = px * 2 + (sub & 1);
            abase[i] = (yy * 28 + xx) * 40 + q * 8;
        } else abase[i] = 0;
    }
    floatx4 acc2[5][4] = {};
    const u16* wtb = w2t + r16 * 32 + q * 8;

    short8 bf[4];
#pragma unroll
    for (int nt = 0; nt < 4; ++nt)
        bf[nt] = *(const short8*)&wtb[nt * 512];

#pragma unroll 1
    for (int tap = 0; tap < 25; ++tap) {
        short8 bfn[4];
        if (tap < 24) {
#pragma unroll
            for (int nt = 0; nt < 4; ++nt)
                bfn[nt] = *(const short8*)&wtb[(tap + 1) * 2048 + nt * 512];
        }
        int r = tap / 5, s = tap - 5 * r;
        int aoff = r * 1120 + s * 40;
#pragma unroll
        for (int i = 0; i < 5; ++i) {
            int mt = w + 4 * i;
            if (mt < 18) {
                short8 af = *(const short8*)&h1t[abase[i] + aoff];
#pragma unroll
                for (int nt = 0; nt < 4; ++nt)
                    acc2[i][nt] = __builtin_amdgcn_mfma_f32_16x16x32_bf16(
                        af, bf[nt], acc2[i][nt], 0, 0, 0);
            }
        }
#pragma unroll
        for (int nt = 0; nt < 4; ++nt) bf[nt] = bfn[nt];
    }
    __syncthreads();  // all A-reads of h1t done; overlay pcaps buffers

    // ---- pool -> hs2[pos*50+oc] f32 @smem[0]; zero hsbuf region ----
    float* hs2 = (float*)smem;  // 3600 f32
#pragma unroll
    for (int i = 0; i < 5; ++i) {
        int mt = w + 4 * i;
        if (mt < 18) {
            int pq = mt * 4 + q;
#pragma unroll
            for (int nt = 0; nt < 4; ++nt) {
                int oc = nt * 16 + r16;
                if (oc < 50) {
                    floatx4 a = acc2[i][nt];
                    hs2[pq * 50 + oc] =
                        fmaxf(fmaxf(a[0], a[1]), fmaxf(a[2], a[3])) + b2[oc];
                }
            }
        }
    }
    for (int i = t; i < 6336; i += 256)   // zero hsbuf [14400,39744) bytes
        ((u32*)smem)[3600 + i] = 0u;
    __syncthreads();

    // ---- pack h_bf (global, stride 1824 u32) + fill hsbuf interior ----
    u16* hsbuf = smem + 7200;             // [176][72] bf16, borders zero
    u32* ho = h_bf + (size_t)b * 1824;
    for (int i = t; i < 1824; i += 256) {
        if (i < 1800) {
            int k2 = 2 * i;
            u32 pk = (u32)f2bf(hs2[k2]) | ((u32)f2bf(hs2[k2 + 1]) << 16);
            ho[i] = pk;
            int pos = k2 / 50;
            int oc  = k2 - 50 * pos;      // even
            int ph  = pos / 12, pw = pos - 12 * ph;
            ((u32*)hsbuf)[((((ph + 2) * 16) + pw + 2) * 72 + oc) >> 1] = pk;
        } else ho[i] = 0u;
    }
    __syncthreads();

    // ---- pcaps via MFMA: M=72 pos (5 m-tiles), N=16 oc, K=64 ----
    int pbase[5];
#pragma unroll
    for (int mt = 0; mt < 5; ++mt) {
        int m  = mt * 16 + r16;
        int ph = m / 12, pw = m - 12 * ph;
        pbase[mt] = (ph * 16 + pw) * 72 + q * 8;
    }
    floatx4 pacc[5] = {};
    const u16* wp = w_pc + r16 * 64 + q * 8;
    const int ntap = (28 - w) >> 2;       // 7,6,6,6
#pragma unroll 1
    for (int tt = 0; tt < ntap; ++tt) {
        int tap = w + 4 * tt;
        short8 b0 = *(const short8*)&wp[tap * 1024];
        short8 b1 = *(const short8*)&wp[tap * 1024 + 32];
        int r = tap / 5, s = tap - 5 * r;
        int aoff = (r * 16 + s) * 72;
#pragma unroll
        for (int mt = 0; mt < 5; ++mt) {
            short8 a0 = *(const short8*)&hsbuf[pbase[mt] + aoff];
            short8 a1 = *(const short8*)&hsbuf[pbase[mt] + aoff + 32];
            pacc[mt] = __builtin_amdgcn_mfma_f32_16x16x32_bf16(a0, b0, pacc[mt], 0, 0, 0);
            pacc[mt] = __builtin_amdgcn_mfma_f32_16x16x32_bf16(a1, b1, pacc[mt], 0, 0, 0);
        }
    }
    __syncthreads();  // hsbuf reads done -> overlay psum

    // psum pitch 17: bank = (16mt+4q+17i+oc) mod 32 spreads q (was 4-way) and
    // makes squash reads (pos*17+c) conflict-light (was pos*16 -> 32-way).
    float* psum = (float*)(smem + 7200);  // [4][80*17] f32, 21760 B
#pragma unroll
    for (int mt = 0; mt < 5; ++mt)
#pragma unroll
        for (int i = 0; i < 4; ++i) {
            int m = mt * 16 + q * 4 + i;
            psum[w * 1360 + m * 17 + r16] = pacc[mt][i];
        }
    __syncthreads();

    for (int i = t; i < 1152; i += 256) {
        int m = i >> 4, oc = i & 15;
        int a = m * 17 + oc;
        float s = psum[a] + psum[1360 + a] + psum[2720 + a] + psum[4080 + a]
                + pcb[oc];
        psum[a] = s;
    }
    __syncthreads();

    // squash + priors -> pri[2][288]
    float* pri = (float*)(smem + 19872);
    for (int r = t; r < 288; r += 256) {
        int sub = r / 72;
        int pos = r - sub * 72;
        float u0 = psum[pos * 17 + 0  + sub];
        float u1 = psum[pos * 17 + 4  + sub];
        float u2 = psum[pos * 17 + 8  + sub];
        float u3 = psum[pos * 17 + 12 + sub];
        float n2 = u0 * u0 + u1 * u1 + u2 * u2 + u3 * u3;
        float scale = (n2 / (1.0f + n2)) * rsqrtf(n2);
        u0 *= scale; u1 *= scale; u2 *= scale; u3 *= scale;
#pragma unroll
        for (int k = 0; k < 2; ++k) {
            const float4 wv = *(const float4*)&rw[(k * 288 + r) * 4];
            pri[k * 288 + r] = u0 * wv.x + u1 * wv.y + u2 * wv.z + u3 * wv.w;
        }
    }
    __syncthreads();

    // dynamic routing (3 iters): wave 0 -> k=0, wave 1 -> k=1
    if (w < 2) {
        const float* pr = &pri[w * 288];
        float p[5];
        bool  val[5];
#pragma unroll
        for (int j = 0; j < 5; ++j) {
            int r  = j * 64 + lane;
            val[j] = r < 288;
            p[j]   = val[j] ? pr[r] : 0.0f;
        }
        float tot = wave_sum(p[0] + p[1] + p[2] + p[3] + p[4]);
        float s = tot * (1.0f / 288.0f);
        float a = s * fabsf(s) / (1.0f + s * s);
#pragma unroll
        for (int it = 0; it < 2; ++it) {
            float l[5];
            float lm = -INFINITY;
#pragma unroll
            for (int j = 0; j < 5; ++j) {
                l[j] = val[j] ? p[j] * a : -INFINITY;
                lm   = fmaxf(lm, l[j]);
            }
            lm = wave_max(lm);
            float se = 0.f, sp = 0.f;
#pragma unroll
            for (int j = 0; j < 5; ++j) {
                float e = val[j] ? expf(l[j] - lm) : 0.f;
                se += e;
                sp += e * p[j];
            }
            se = wave_sum(se);
            sp = wave_sum(sp);
            float sv = sp / se;
            float v  = sv * fabsf(sv) / (1.0f + sv * sv);
            if (it == 0) a += v;
            else if (lane == 0) cbuf[b * 2 + w] = v;
        }
    }
}

// ---------- Kernel 2: fc1 64x32-tile BK=64 dbuf GEMM + fused fc2 -----------
// grid (32,16) = 512 blocks -> 2 blocks/CU: sibling block's waves fill the
// vmcnt/barrier drain stalls (m114). Same-x blocks share an XCD across y
// (id = x+32y, XCD = id%8 = x%8) -> A tiles stay L2-local for all 16 n-passes.
__global__ __launch_bounds__(256) void k_fc1(
    const u16* __restrict__ h_bf, const u16* __restrict__ w_bf,
    const float* __restrict__ cc, const float* __restrict__ w,
    const float* __restrict__ bias, const float* __restrict__ f2w,
    float* __restrict__ out)
{
    __shared__ __align__(16) u16 As[2][64 * 72];  // pitch 72 (144 B): 2-way banks
    __shared__ __align__(16) u16 Bs[2][32 * 72];
    const int t  = threadIdx.x;
    const int m0 = blockIdx.x * 64;
    const int n0 = blockIdx.y * 32;
    const int row = t >> 2, seg = t & 3;          // A: 64 rows x 4 segs of 16
    const bool bload = (t < 128);                 // B: 32 rows x 4 segs of 16
    const u16* ha = &h_bf[(size_t)(m0 + row) * KP + seg * 16];
    const u16* wa = &w_bf[(size_t)(n0 + (row & 31)) * KP + seg * 16];
    short8 a0 = *(const short8*)ha;
    short8 a1 = *(const short8*)(ha + 8);
    short8 b0 = {}, b1 = {};
    if (bload) { b0 = *(const short8*)wa; b1 = *(const short8*)(wa + 8); }
    const int lane = t & 63, wv = t >> 6;
    const int r16 = lane & 15, q = lane >> 4;
    const int awr = row * 72 + seg * 16;
    const int bwr = (row & 31) * 72 + seg * 16;
    const int ar  = (wv * 16 + r16) * 72 + q * 8;
    const int br  = r16 * 72 + q * 8;
    floatx4 acc[2] = {};
#pragma unroll 1
    for (int it = 0; it < 57; ++it) {
        const int buf = it & 1;
        *(short8*)&As[buf][awr]     = a0;
        *(short8*)&As[buf][awr + 8] = a1;
        if (bload) {
            *(short8*)&Bs[buf][bwr]     = b0;
            *(short8*)&Bs[buf][bwr + 8] = b1;
        }
        if (it < 56) {
            const u16* han = ha + (it + 1) * 64;
            a0 = *(const short8*)han;
            a1 = *(const short8*)(han + 8);
            if (bload) {
                const u16* wan = wa + (it + 1) * 64;
                b0 = *(const short8*)wan;
                b1 = *(const short8*)(wan + 8);
            }
        }
        __syncthreads();
#pragma unroll
        for (int s = 0; s < 2; ++s) {
            short8 af = *(const short8*)&As[buf][ar + s * 32];
#pragma unroll
            for (int nt = 0; nt < 2; ++nt) {
                short8 bfv = *(const short8*)&Bs[buf][br + nt * 1152 + s * 32];
                acc[nt] = __builtin_amdgcn_mfma_f32_16x16x32_bf16(
                    af, bfv, acc[nt], 0, 0, 0);
            }
        }
    }
    // epilogue: bias + caps cols + relu, dot with fc2 rows, atomic into out
    const int mbase = m0 + wv * 16 + q * 4;
    float s0[4] = {0.f, 0.f, 0.f, 0.f};
    float s1[4] = {0.f, 0.f, 0.f, 0.f};
#pragma unroll
    for (int nt = 0; nt < 2; ++nt) {
        int n = n0 + nt * 16 + r16;
        if (n < 500) {
            float bn  = bias[n];
            float wc0 = w[(size_t)n * 3602 + 3600];
            float wc1 = w[(size_t)n * 3602 + 3601];
            float w20 = f2w[n];
            float w21 = f2w[502 + n];
#pragma unroll
            for (int i = 0; i < 4; ++i) {
                int m = mbase + i;
                float v = fmaxf(acc[nt][i] + bn + cc[m * 2] * wc0
                                + cc[m * 2 + 1] * wc1, 0.f);
                s0[i] += v * w20;
                s1[i] += v * w21;
            }
        }
    }
#pragma unroll
    for (int i = 0; i < 4; ++i) {
        float a0r = s0[i], a1r = s1[i];
#pragma unroll
        for (int off = 1; off <= 8; off <<= 1) {
            a0r += __shfl_xor(a0r, off);
            a1r += __shfl_xor(a1r, off);
        }
        if (r16 == 0) {
            int m = mbase + i;
            atomicAdd(&out[m * 2], a0r);
            atomicAdd(&out[m * 2 + 1], a1r);
        }
    }
}

// ---------------------------------------------------------------------------
extern "C" void kernel_launch(void* const* d_in, const int* in_sizes, int n_in,
                              void* d_out, int out_size, void* d_ws, size_t ws_size,
                              hipStream_t stream) {
    const float* x    = (const float*)d_in[0];
    const float* y    = (const float*)d_in[1];
    const float* c1w  = (const float*)d_in[2];
    const float* c1b  = (const float*)d_in[3];
    const float* c2w  = (const float*)d_in[4];
    const float* c2b  = (const float*)d_in[5];
    const float* pcw  = (const float*)d_in[6];
    const float* pcb  = (const float*)d_in[7];
    const float* rw   = (const float*)d_in[8];
    const float* f1w  = (const float*)d_in[9];
    const float* f1b  = (const float*)d_in[10];
    const float* f2w  = (const float*)d_in[11];
    const float* f2b  = (const float*)d_in[12];
    float* out = (float*)d_out;

    // workspace layout
    u32*   h_bf = (u32*)d_ws;                           // 2048*1824 u32
    u16*   w_bf = (u16*)(h_bf + (size_t)BATCH * 1824);  // 512*3648 u16
    u16*   w2t  = w_bf + (size_t)512 * KP;              // 25*64*32 u16
    u16*   w_pc = w2t + 51200;                          // 25*16*64 u16
    u16*   w1t  = w_pc + 25600;                         // 32*32 u16
    float* cbuf = (float*)(w1t + 1024);                 // 4096 f32

    k_prep<<<548, 256, 0, stream>>>(f1w, w_bf, c2w, w2t, pcw, w_pc, c1w, w1t,
                                    y, f2w, f2b, out);
    k_convs<<<BATCH, 256, 0, stream>>>(x, w1t, c1b, w2t, c2b, w_pc, pcb, rw,
                                       h_bf, cbuf);
    dim3 g4(32, 16);
    k_fc1<<<g4, 256, 0, stream>>>((const u16*)h_bf, w_bf, cbuf, f1w, f1b,
                                  f2w, out);
}

// Round 12
// 236.628 us; speedup vs baseline: 1.0078x; 1.0078x over previous
//
#include <hip/hip_runtime.h>
#include <math.h>

// ---------------------------------------------------------------------------
// Model: conv1(5x5,20)+pool2 -> conv2(5x5,50)+pool2 -> pcaps(5x5 pad2,16)
//        -> squash -> priors -> dynamic routing(3) -> fc1(relu) -> fc2
// B=2048. conv1/conv2/pcaps/fc1 via bf16 MFMA (16x16x32).
// k_fc1 v4 (m97 pattern): async global->LDS staging (global_load_lds w=16),
// 128x64 tile, K-split 4 (raw partials -> f1buf), 2-barrier K-loop.
// k_fc2: sum partials + bias/caps/relu + fc2 dot -> out.
// h_bf POSITION-MAJOR: k' = pos*50 + oc, padded to 3712 (=4*928, 928=29*32).
// ---------------------------------------------------------------------------

#define BATCH 2048
#define KP 3712          // padded K for fc1 (4 k-splits x 928, 928 = 29*32)

typedef __attribute__((ext_vector_type(8))) short short8;
typedef __attribute__((ext_vector_type(4))) float floatx4;
typedef unsigned short u16;
typedef unsigned int   u32;

// async global->LDS: HW writes lane i's 16B to (wave-uniform lds base)+i*16
#define GLD(gp, lp) __builtin_amdgcn_global_load_lds( \
    (const __attribute__((address_space(1))) u32*)(gp), \
    (__attribute__((address_space(3))) u32*)(lp), 16, 0, 0)

__device__ inline float wave_sum(float v) {
#pragma unroll
    for (int off = 32; off >= 1; off >>= 1) v += __shfl_xor(v, off);
    return v;
}
__device__ inline float wave_max(float v) {
#pragma unroll
    for (int off = 32; off >= 1; off >>= 1) v = fmaxf(v, __shfl_xor(v, off));
    return v;
}
__device__ inline u16 f2bf(float f) {  // RNE fp32->bf16 (finite)
    u32 u = __float_as_uint(f);
    u32 r = (u + 0x7FFFu + ((u >> 16) & 1u)) >> 16;
    return (u16)r;
}

// ---------- Kernel 0: weight conversions -----------------------------------
// blk <  500 : fc1 weights row n -> w_bf[n][KP] bf16, K-permuted, via LDS
// blk == 500 : zero w_bf rows 500..511
// blk <  526 : conv2 weights -> w2t[25][64][32] bf16
// blk <  539 : pcaps weights -> w_pc[25][16][64] bf16
// blk == 539 : conv1 weights -> w1t[32][32] bf16
// blk == 540 : wtab[n][8] = {f1b, wcap0, wcap1, f2w0, f2w1, 0,0,0}
__global__ __launch_bounds__(256) void k_prep(
    const float* __restrict__ fw,  u16* __restrict__ w_bf,
    const float* __restrict__ w2,  u16* __restrict__ w2t,
    const float* __restrict__ pcw, u16* __restrict__ w_pc,
    const float* __restrict__ w1,  u16* __restrict__ w1t,
    const float* __restrict__ f1b, const float* __restrict__ f2w,
    float* __restrict__ wtab)
{
    __shared__ __align__(16) float srow[3600];
    const int blk = blockIdx.x, t = threadIdx.x;
    if (blk < 500) {
        const int n = blk;
        const float* src = fw + (size_t)n * 3602;
        for (int i = t; i < 1800; i += 256)
            *(float2*)&srow[2 * i] = *(const float2*)&src[2 * i];
        __syncthreads();
        u32* dst = (u32*)(w_bf + (size_t)n * KP);
        for (int i = t; i < 1856; i += 256) {
            int k2 = 2 * i;
            u32 pk = 0u;
            if (k2 < 3600) {
                int pos = k2 / 50, oc = k2 - 50 * pos;
                pk = (u32)f2bf(srow[oc * 72 + pos])
                   | ((u32)f2bf(srow[(oc + 1) * 72 + pos]) << 16);
            }
            dst[i] = pk;
        }
    } else if (blk == 500) {
        u32* z = (u32*)(w_bf + (size_t)500 * KP);
        for (int i = t; i < 22272; i += 256) z[i] = 0u;   // 12 * 1856
    } else if (blk < 526) {
        int g   = (blk - 501) * 256 + t;
        int idx = g * 8;
        int tap = idx >> 11;
        int oc  = (idx >> 5) & 63;
        int ic0 = idx & 31;
        u16 v[8];
#pragma unroll
        for (int j = 0; j < 8; ++j) {
            int ic = ic0 + j;
            float f = (ic < 20 && oc < 50) ? w2[oc * 500 + ic * 25 + tap] : 0.f;
            v[j] = f2bf(f);
        }
        *(short8*)&w2t[idx] = *(short8*)v;
    } else if (blk < 539) {
        int g = (blk - 526) * 256 + t;
        if (g >= 3200) return;
        int idx = g * 8;
        int tap = idx >> 10;
        int rem = idx & 1023;
        int oc  = rem >> 6;
        int ic0 = rem & 63;
        u16 v[8];
#pragma unroll
        for (int j = 0; j < 8; ++j) {
            int ic = ic0 + j;
            float f = (ic < 50) ? pcw[(oc * 50 + ic) * 25 + tap] : 0.f;
            v[j] = f2bf(f);
        }
        *(short8*)&w_pc[idx] = *(short8*)v;
    } else if (blk == 539) {
        if (t < 128) {
            int n  = t >> 2;
            int k0 = (t & 3) * 8;
            u16 v[8];
#pragma unroll
            for (int j = 0; j < 8; ++j) {
                int k = k0 + j;
                float f = (n < 20 && k < 25) ? w1[n * 25 + k] : 0.f;
                v[j] = f2bf(f);
            }
            *(short8*)&w1t[t * 8] = *(short8*)v;
        }
    } else {
        for (int nn = t; nn < 512; nn += 256) {
            float bias = 0.f, wc0 = 0.f, wc1 = 0.f, f20 = 0.f, f21 = 0.f;
            if (nn < 500) {
                bias = f1b[nn];
                wc0  = fw[(size_t)nn * 3602 + 3600];
                wc1  = fw[(size_t)nn * 3602 + 3601];
                f20  = f2w[nn];
                f21  = f2w[502 + nn];
            }
            *(float4*)&wtab[nn * 8]     = make_float4(bias, wc0, wc1, f20);
            *(float4*)&wtab[nn * 8 + 4] = make_float4(f21, 0.f, 0.f, 0.f);
        }
    }
}

// ---------- Kernel 1: conv1+conv2 (MFMA) + pcaps (MFMA) + routing ----------
// (round-8 structure; h_bf stride 1856 u32)
__global__ __launch_bounds__(256, 3) void k_convs(
    const float* __restrict__ x, const u16* __restrict__ w1t,
    const float* __restrict__ b1, const u16* __restrict__ w2t,
    const float* __restrict__ b2, const u16* __restrict__ w_pc,
    const float* __restrict__ pcb, const float* __restrict__ rw,
    u32* __restrict__ h_bf, float* __restrict__ cbuf)
{
    __shared__ __align__(16) u16 smem[24704];
    u16* h1t = smem;            // 17920 shorts
    u16* xbf = smem + 17920;    // 2304 shorts
    u16* im2 = smem + 20224;    // 4480 shorts

    const int t = threadIdx.x;
    const int b = blockIdx.x;

    for (int i = t; i < 2688; i += 256) {
        int pos = i / 6, c = i - 6 * pos;
        ((u32*)h1t)[pos * 20 + 10 + c] = 0u;
    }
    const float* xb = x + b * 2160;
    for (int i = t; i < 2160; i += 256) {
        int r = i / 60, c = i - 60 * r;
        xbf[r * 64 + c] = f2bf(xb[i]);
    }
    __syncthreads();

    const int lane = t & 63, w = t >> 6;
    const int r16  = lane & 15;
    const int q    = lane >> 4;

    // ---- conv1 via MFMA, 16 chunks of 2 pre-pool rows (112 positions) ----
    short8 w1f[2];
#pragma unroll
    for (int nt = 0; nt < 2; ++nt)
        w1f[nt] = *(const short8*)&w1t[(nt * 16 + r16) * 32 + q * 8];

    const int p_   = t;
    const int px_  = p_ >> 2;
    const int dy_  = (p_ & 3) >> 1, dx_ = p_ & 1;
    const int xc_  = 2 * px_ + dx_;
    const int j0_  = xc_ >> 1;
    const int par_ = xc_ & 1;

#pragma unroll 1
    for (int c = 0; c < 16; ++c) {
        if (t < 112) {
            u16 tap[25];
#pragma unroll
            for (int r = 0; r < 5; ++r) {
                const u32* U = (const u32*)&xbf[(2 * c + dy_ + r) * 64];
                u32 A0 = U[j0_], A1 = U[j0_ + 1], A2 = U[j0_ + 2];
                u16 e0 = par_ ? (u16)(A0 >> 16) : (u16)A0;
                u16 e1 = par_ ? (u16)A1         : (u16)(A0 >> 16);
                u16 e2 = par_ ? (u16)(A1 >> 16) : (u16)A1;
                u16 e3 = par_ ? (u16)A2         : (u16)(A1 >> 16);
                u16 e4 = par_ ? (u16)(A2 >> 16) : (u16)A2;
                tap[r * 5 + 0] = e0; tap[r * 5 + 1] = e1; tap[r * 5 + 2] = e2;
                tap[r * 5 + 3] = e3; tap[r * 5 + 4] = e4;
            }
            u32 ow[16];
#pragma unroll
            for (int j = 0; j < 12; ++j)
                ow[j] = (u32)tap[2 * j] | ((u32)tap[2 * j + 1] << 16);
            ow[12] = (u32)tap[24];
            ow[13] = 0u; ow[14] = 0u; ow[15] = 0u;
            u32* dst = (u32*)&im2[p_ * 40];
            *(uint4*)&dst[0]  = make_uint4(ow[0],  ow[1],  ow[2],  ow[3]);
            *(uint4*)&dst[4]  = make_uint4(ow[4],  ow[5],  ow[6],  ow[7]);
            *(uint4*)&dst[8]  = make_uint4(ow[8],  ow[9],  ow[10], ow[11]);
            *(uint4*)&dst[12] = make_uint4(ow[12], ow[13], ow[14], ow[15]);
        }
        __syncthreads();
#pragma unroll
        for (int mi = 0; mi < 2; ++mi) {
            int mt = w + 4 * mi;
            if (mt < 7) {
                short8 af = *(const short8*)&im2[(mt * 16 + r16) * 40 + q * 8];
                floatx4 a1[2] = {};
#pragma unroll
                for (int nt = 0; nt < 2; ++nt)
                    a1[nt] = __builtin_amdgcn_mfma_f32_16x16x32_bf16(
                        af, w1f[nt], a1[nt], 0, 0, 0);
                int pq = mt * 4 + q;
#pragma unroll
                for (int nt = 0; nt < 2; ++nt) {
                    int oc = nt * 16 + r16;
                    if (oc < 20) {
                        floatx4 a = a1[nt];
                        float v = fmaxf(fmaxf(a[0], a[1]), fmaxf(a[2], a[3]))
                                + b1[oc];
                        h1t[(c * 28 + pq) * 40 + oc] = f2bf(v);
                    }
                }
            }
        }
        __syncthreads();
    }

    // ---- conv2 via MFMA: M=288 Z-ordered pre-pool, N=64, K=32, 25 taps ----
    int abase[5];
#pragma unroll
    for (int i = 0; i < 5; ++i) {
        int mt = w + 4 * i;
        if (mt < 18) {
            int m  = mt * 16 + r16;
            int pq = m >> 2, sub = m & 3;
            int py = pq / 12, px = pq - py * 12;
            int yy = py * 2 + (sub >> 1);
            int xx = px * 2 + (sub & 1);
            abase[i] = (yy * 28 + xx) * 40 + q * 8;
        } else abase[i] = 0;
    }
    floatx4 acc2[5][4] = {};
    const u16* wtb = w2t + r16 * 32 + q * 8;

    short8 bf[4];
#pragma unroll
    for (int nt = 0; nt < 4; ++nt)
        bf[nt] = *(const short8*)&wtb[nt * 512];

#pragma unroll 1
    for (int tap = 0; tap < 25; ++tap) {
        short8 bfn[4];
        if (tap < 24) {
#pragma unroll
            for (int nt = 0; nt < 4; ++nt)
                bfn[nt] = *(const short8*)&wtb[(tap + 1) * 2048 + nt * 512];
        }
        int r = tap / 5, s = tap - 5 * r;
        int aoff = r * 1120 + s * 40;
#pragma unroll
        for (int i = 0; i < 5; ++i) {
            int mt = w + 4 * i;
            if (mt < 18) {
                short8 af = *(const short8*)&h1t[abase[i] + aoff];
#pragma unroll
                for (int nt = 0; nt < 4; ++nt)
                    acc2[i][nt] = __builtin_amdgcn_mfma_f32_16x16x32_bf16(
                        af, bf[nt], acc2[i][nt], 0, 0, 0);
            }
        }
#pragma unroll
        for (int nt = 0; nt < 4; ++nt) bf[nt] = bfn[nt];
    }
    __syncthreads();

    // ---- pool -> hs2[pos*50+oc] f32 @smem[0]; zero hsbuf region ----
    float* hs2 = (float*)smem;
#pragma unroll
    for (int i = 0; i < 5; ++i) {
        int mt = w + 4 * i;
        if (mt < 18) {
            int pq = mt * 4 + q;
#pragma unroll
            for (int nt = 0; nt < 4; ++nt) {
                int oc = nt * 16 + r16;
                if (oc < 50) {
                    floatx4 a = acc2[i][nt];
                    hs2[pq * 50 + oc] =
                        fmaxf(fmaxf(a[0], a[1]), fmaxf(a[2], a[3])) + b2[oc];
                }
            }
        }
    }
    for (int i = t; i < 6336; i += 256)
        ((u32*)smem)[3600 + i] = 0u;
    __syncthreads();

    // ---- pack h_bf (stride 1856 u32) + fill hsbuf interior ----
    u16* hsbuf = smem + 7200;
    u32* ho = h_bf + (size_t)b * 1856;
    for (int i = t; i < 1856; i += 256) {
        if (i < 1800) {
            int k2 = 2 * i;
            u32 pk = (u32)f2bf(hs2[k2]) | ((u32)f2bf(hs2[k2 + 1]) << 16);
            ho[i] = pk;
            int pos = k2 / 50;
            int oc  = k2 - 50 * pos;
            int ph  = pos / 12, pw = pos - 12 * ph;
            ((u32*)hsbuf)[((((ph + 2) * 16) + pw + 2) * 72 + oc) >> 1] = pk;
        } else ho[i] = 0u;
    }
    __syncthreads();

    // ---- pcaps via MFMA ----
    int pbase[5];
#pragma unroll
    for (int mt = 0; mt < 5; ++mt) {
        int m  = mt * 16 + r16;
        int ph = m / 12, pw = m - 12 * ph;
        pbase[mt] = (ph * 16 + pw) * 72 + q * 8;
    }
    floatx4 pacc[5] = {};
    const u16* wp = w_pc + r16 * 64 + q * 8;
    const int ntap = (28 - w) >> 2;
#pragma unroll 1
    for (int tt = 0; tt < ntap; ++tt) {
        int tap = w + 4 * tt;
        short8 b0 = *(const short8*)&wp[tap * 1024];
        short8 b1 = *(const short8*)&wp[tap * 1024 + 32];
        int r = tap / 5, s = tap - 5 * r;
        int aoff = (r * 16 + s) * 72;
#pragma unroll
        for (int mt = 0; mt < 5; ++mt) {
            short8 a0 = *(const short8*)&hsbuf[pbase[mt] + aoff];
            short8 a1 = *(const short8*)&hsbuf[pbase[mt] + aoff + 32];
            pacc[mt] = __builtin_amdgcn_mfma_f32_16x16x32_bf16(a0, b0, pacc[mt], 0, 0, 0);
            pacc[mt] = __builtin_amdgcn_mfma_f32_16x16x32_bf16(a1, b1, pacc[mt], 0, 0, 0);
        }
    }
    __syncthreads();

    float* psum = (float*)(smem + 7200);  // [4][80*17] f32
#pragma unroll
    for (int mt = 0; mt < 5; ++mt)
#pragma unroll
        for (int i = 0; i < 4; ++i) {
            int m = mt * 16 + q * 4 + i;
            psum[w * 1360 + m * 17 + r16] = pacc[mt][i];
        }
    __syncthreads();

    for (int i = t; i < 1152; i += 256) {
        int m = i >> 4, oc = i & 15;
        int a = m * 17 + oc;
        float s = psum[a] + psum[1360 + a] + psum[2720 + a] + psum[4080 + a]
                + pcb[oc];
        psum[a] = s;
    }
    __syncthreads();

    float* pri = (float*)(smem + 19872);
    for (int r = t; r < 288; r += 256) {
        int sub = r / 72;
        int pos = r - sub * 72;
        float u0 = psum[pos * 17 + 0  + sub];
        float u1 = psum[pos * 17 + 4  + sub];
        float u2 = psum[pos * 17 + 8  + sub];
        float u3 = psum[pos * 17 + 12 + sub];
        float n2 = u0 * u0 + u1 * u1 + u2 * u2 + u3 * u3;
        float scale = (n2 / (1.0f + n2)) * rsqrtf(n2);
        u0 *= scale; u1 *= scale; u2 *= scale; u3 *= scale;
#pragma unroll
        for (int k = 0; k < 2; ++k) {
            const float4 wv = *(const float4*)&rw[(k * 288 + r) * 4];
            pri[k * 288 + r] = u0 * wv.x + u1 * wv.y + u2 * wv.z + u3 * wv.w;
        }
    }
    __syncthreads();

    if (w < 2) {
        const float* pr = &pri[w * 288];
        float p[5];
        bool  val[5];
#pragma unroll
        for (int j = 0; j < 5; ++j) {
            int r  = j * 64 + lane;
            val[j] = r < 288;
            p[j]   = val[j] ? pr[r] : 0.0f;
        }
        float tot = wave_sum(p[0] + p[1] + p[2] + p[3] + p[4]);
        float s = tot * (1.0f / 288.0f);
        float a = s * fabsf(s) / (1.0f + s * s);
#pragma unroll
        for (int it = 0; it < 2; ++it) {
            float l[5];
            float lm = -INFINITY;
#pragma unroll
            for (int j = 0; j < 5; ++j) {
                l[j] = val[j] ? p[j] * a : -INFINITY;
                lm   = fmaxf(lm, l[j]);
            }
            lm = wave_max(lm);
            float se = 0.f, sp = 0.f;
#pragma unroll
            for (int j = 0; j < 5; ++j) {
                float e = val[j] ? expf(l[j] - lm) : 0.f;
                se += e;
                sp += e * p[j];
            }
            se = wave_sum(se);
            sp = wave_sum(sp);
            float sv = sp / se;
            float v  = sv * fabsf(sv) / (1.0f + sv * sv);
            if (it == 0) a += v;
            else if (lane == 0) cbuf[b * 2 + w] = v;
        }
    }
}

// ---------- Kernel 2: fc1 partial GEMM, m97-style async staging ------------
// grid (16, 8, 4): 128m x 64n tile, k-split s covers K range [s*928,(s+1)*928)
// 29 iters of BK=32: stage As[128][32]+Bs[64][32] via global_load_lds(16B),
// 8 MFMAs/wave/iter. Raw partial C -> f1buf[s][2048][512] f32.
__global__ __launch_bounds__(256) void k_fc1(
    const u16* __restrict__ h_bf, const u16* __restrict__ w_bf,
    float* __restrict__ f1buf)
{
    __shared__ __align__(16) u16 As[128 * 32];   // 8192 B
    __shared__ __align__(16) u16 Bs[64 * 32];    // 4096 B
    const int t = threadIdx.x;
    const int lane = t & 63, w = t >> 6;
    const int m0 = blockIdx.x * 128;
    const int n0 = blockIdx.y * 64;
    const int s  = blockIdx.z;
    const int k0 = s * 928;

    // staging: A tile = 8 wave-issues (idx=(w*2+j)*64+lane), B = 4 (idx=w*64+lane)
    const int ai0 = (w * 2) * 64 + lane;
    const int ai1 = (w * 2 + 1) * 64 + lane;
    const int bi  = w * 64 + lane;
    const u16* ga0 = h_bf + (size_t)(m0 + (ai0 >> 2)) * KP + k0 + (ai0 & 3) * 8;
    const u16* ga1 = h_bf + (size_t)(m0 + (ai1 >> 2)) * KP + k0 + (ai1 & 3) * 8;
    const u16* gb  = w_bf + (size_t)(n0 + (bi  >> 2)) * KP + k0 + (bi  & 3) * 8;
    u16* lA0 = As + (w * 2) * 512;       // wave-uniform LDS bases
    u16* lA1 = As + (w * 2 + 1) * 512;
    u16* lB  = Bs + w * 512;

    const int r16 = lane & 15, q = lane >> 4;
    const int ar = (w * 32 + r16) * 32 + q * 8;   // wave w owns m rows [32w,32w+32)
    const int br = r16 * 32 + q * 8;

    floatx4 acc[2][4] = {};
#pragma unroll 1
    for (int it = 0; it < 29; ++it) {
        const int ko = it * 32;
        GLD(ga0 + ko, lA0);
        GLD(ga1 + ko, lA1);
        GLD(gb + ko, lB);
        __syncthreads();   // drains staging (vmcnt0): tile ready
        short8 af0 = *(const short8*)&As[ar];
        short8 af1 = *(const short8*)&As[ar + 512];
#pragma unroll
        for (int nt = 0; nt < 4; ++nt) {
            short8 bfv = *(const short8*)&Bs[br + nt * 512];
            acc[0][nt] = __builtin_amdgcn_mfma_f32_16x16x32_bf16(af0, bfv, acc[0][nt], 0, 0, 0);
            acc[1][nt] = __builtin_amdgcn_mfma_f32_16x16x32_bf16(af1, bfv, acc[1][nt], 0, 0, 0);
        }
        __syncthreads();   // all LDS reads done before next stage overwrites
    }

    float* fo = f1buf + (size_t)s * (2048 * 512);
    const int mb = m0 + w * 32;
#pragma unroll
    for (int mt2 = 0; mt2 < 2; ++mt2)
#pragma unroll
        for (int nt = 0; nt < 4; ++nt) {
            int n = n0 + nt * 16 + r16;
#pragma unroll
            for (int i = 0; i < 4; ++i) {
                int m = mb + mt2 * 16 + q * 4 + i;
                fo[(size_t)m * 512 + n] = acc[mt2][nt][i];
            }
        }
}

// ---------- Kernel 3: fc2 final — sum partials, relu, dot ------------------
// one wave per sample b: raw = sum_s f1buf[s][b][n]; v = relu(raw + bias +
// caps); out[b][j] = f2b[j] + y-terms + sum_n v * f2w[j][n]
__global__ __launch_bounds__(256) void k_fc2(
    const float* __restrict__ f1buf, const float* __restrict__ wtab,
    const float* __restrict__ cc, const float* __restrict__ y,
    const float* __restrict__ f2w, const float* __restrict__ f2b,
    float* __restrict__ out)
{
    const int b = blockIdx.x * 4 + (threadIdx.x >> 6);
    const int lane = threadIdx.x & 63;
    const float* fb = f1buf + (size_t)b * 512;
    const float c0 = cc[b * 2], c1 = cc[b * 2 + 1];
    float s0 = 0.f, s1 = 0.f;
#pragma unroll
    for (int j = 0; j < 8; ++j) {
        int n = lane + j * 64;
        float raw = fb[n] + fb[1048576 + n] + fb[2097152 + n] + fb[3145728 + n];
        float4 t0 = *(const float4*)&wtab[n * 8];
        float  f21 = wtab[n * 8 + 4];
        float v = fmaxf(raw + t0.x + c0 * t0.y + c1 * t0.z, 0.f);
        s0 += v * t0.w;
        s1 += v * f21;
    }
    s0 = wave_sum(s0);
    s1 = wave_sum(s1);
    if (lane == 0) {
        float y0 = y[b * 2], y1 = y[b * 2 + 1];
        out[b * 2]     = s0 + f2b[0] + y0 * f2w[500] + y1 * f2w[501];
        out[b * 2 + 1] = s1 + f2b[1] + y0 * f2w[1002] + y1 * f2w[1003];
    }
}

// ---------------------------------------------------------------------------
extern "C" void kernel_launch(void* const* d_in, const int* in_sizes, int n_in,
                              void* d_out, int out_size, void* d_ws, size_t ws_size,
                              hipStream_t stream) {
    const float* x    = (const float*)d_in[0];
    const float* y    = (const float*)d_in[1];
    const float* c1w  = (const float*)d_in[2];
    const float* c1b  = (const float*)d_in[3];
    const float* c2w  = (const float*)d_in[4];
    const float* c2b  = (const float*)d_in[5];
    const float* pcw  = (const float*)d_in[6];
    const float* pcb  = (const float*)d_in[7];
    const float* rw   = (const float*)d_in[8];
    const float* f1w  = (const float*)d_in[9];
    const float* f1b  = (const float*)d_in[10];
    const float* f2w  = (const float*)d_in[11];
    const float* f2b  = (const float*)d_in[12];
    float* out = (float*)d_out;

    // workspace layout (~36 MB)
    u32*   h_bf  = (u32*)d_ws;                            // 2048*1856 u32
    u16*   w_bf  = (u16*)(h_bf + (size_t)BATCH * 1856);   // 512*3712 u16
    u16*   w2t   = w_bf + (size_t)512 * KP;               // 25*64*32 u16
    u16*   w_pc  = w2t + 51200;                           // 25*16*64 u16
    u16*   w1t   = w_pc + 25600;                          // 32*32 u16
    float* cbuf  = (float*)(w1t + 1024);                  // 4096 f32
    float* wtab  = cbuf + 4096;                           // 4096 f32
    float* f1buf = wtab + 4096;                           // 4*2048*512 f32

    k_prep<<<541, 256, 0, stream>>>(f1w, w_bf, c2w, w2t, pcw, w_pc, c1w, w1t,
                                    f1b, f2w, wtab);
    k_convs<<<BATCH, 256, 0, stream>>>(x, w1t, c1b, w2t, c2b, w_pc, pcb, rw,
                                       h_bf, cbuf);
    dim3 g4(16, 8, 4);
    k_fc1<<<g4, 256, 0, stream>>>((const u16*)h_bf, w_bf, f1buf);
    k_fc2<<<BATCH / 4, 256, 0, stream>>>(f1buf, wtab, cbuf, y, f2w, f2b, out);
}

// Round 13
// 235.538 us; speedup vs baseline: 1.0124x; 1.0046x over previous
//
#include <hip/hip_runtime.h>
#include <math.h>

// ---------------------------------------------------------------------------
// Model: conv1(5x5,20)+pool2 -> conv2(5x5,50)+pool2 -> pcaps(5x5 pad2,16)
//        -> squash -> priors -> dynamic routing(3) -> fc1(relu) -> fc2
// B=2048. conv1/conv2/pcaps/fc1 via bf16 MFMA (16x16x32).
// Round 13: im2col chunk XOR-swizzle (col = k ^ ((row>>3)&3)) kills the
// 8-way LDS write conflicts of the pitch-40 layout (2-way residual = free).
// k_fc1 v4 (m97 pattern) + k_fc2 unchanged from round 12.
// h_bf POSITION-MAJOR: k' = pos*50 + oc, padded to 3712 (=4*928, 928=29*32).
// ---------------------------------------------------------------------------

#define BATCH 2048
#define KP 3712          // padded K for fc1 (4 k-splits x 928, 928 = 29*32)

typedef __attribute__((ext_vector_type(8))) short short8;
typedef __attribute__((ext_vector_type(4))) float floatx4;
typedef unsigned short u16;
typedef unsigned int   u32;

// async global->LDS: HW writes lane i's 16B to (wave-uniform lds base)+i*16
#define GLD(gp, lp) __builtin_amdgcn_global_load_lds( \
    (const __attribute__((address_space(1))) u32*)(gp), \
    (__attribute__((address_space(3))) u32*)(lp), 16, 0, 0)

__device__ inline float wave_sum(float v) {
#pragma unroll
    for (int off = 32; off >= 1; off >>= 1) v += __shfl_xor(v, off);
    return v;
}
__device__ inline float wave_max(float v) {
#pragma unroll
    for (int off = 32; off >= 1; off >>= 1) v = fmaxf(v, __shfl_xor(v, off));
    return v;
}
__device__ inline u16 f2bf(float f) {  // RNE fp32->bf16 (finite)
    u32 u = __float_as_uint(f);
    u32 r = (u + 0x7FFFu + ((u >> 16) & 1u)) >> 16;
    return (u16)r;
}

// ---------- Kernel 0: weight conversions -----------------------------------
// blk <  500 : fc1 weights row n -> w_bf[n][KP] bf16, K-permuted, via LDS
// blk == 500 : zero w_bf rows 500..511
// blk <  526 : conv2 weights -> w2t[25][64][32] bf16
// blk <  539 : pcaps weights -> w_pc[25][16][64] bf16
// blk == 539 : conv1 weights -> w1t[32][32] bf16
// blk == 540 : wtab[n][8] = {f1b, wcap0, wcap1, f2w0, f2w1, 0,0,0}
__global__ __launch_bounds__(256) void k_prep(
    const float* __restrict__ fw,  u16* __restrict__ w_bf,
    const float* __restrict__ w2,  u16* __restrict__ w2t,
    const float* __restrict__ pcw, u16* __restrict__ w_pc,
    const float* __restrict__ w1,  u16* __restrict__ w1t,
    const float* __restrict__ f1b, const float* __restrict__ f2w,
    float* __restrict__ wtab)
{
    __shared__ __align__(16) float srow[3600];
    const int blk = blockIdx.x, t = threadIdx.x;
    if (blk < 500) {
        const int n = blk;
        const float* src = fw + (size_t)n * 3602;
        for (int i = t; i < 1800; i += 256)
            *(float2*)&srow[2 * i] = *(const float2*)&src[2 * i];
        __syncthreads();
        u32* dst = (u32*)(w_bf + (size_t)n * KP);
        for (int i = t; i < 1856; i += 256) {
            int k2 = 2 * i;
            u32 pk = 0u;
            if (k2 < 3600) {
                int pos = k2 / 50, oc = k2 - 50 * pos;
                pk = (u32)f2bf(srow[oc * 72 + pos])
                   | ((u32)f2bf(srow[(oc + 1) * 72 + pos]) << 16);
            }
            dst[i] = pk;
        }
    } else if (blk == 500) {
        u32* z = (u32*)(w_bf + (size_t)500 * KP);
        for (int i = t; i < 22272; i += 256) z[i] = 0u;   // 12 * 1856
    } else if (blk < 526) {
        int g   = (blk - 501) * 256 + t;
        int idx = g * 8;
        int tap = idx >> 11;
        int oc  = (idx >> 5) & 63;
        int ic0 = idx & 31;
        u16 v[8];
#pragma unroll
        for (int j = 0; j < 8; ++j) {
            int ic = ic0 + j;
            float f = (ic < 20 && oc < 50) ? w2[oc * 500 + ic * 25 + tap] : 0.f;
            v[j] = f2bf(f);
        }
        *(short8*)&w2t[idx] = *(short8*)v;
    } else if (blk < 539) {
        int g = (blk - 526) * 256 + t;
        if (g >= 3200) return;
        int idx = g * 8;
        int tap = idx >> 10;
        int rem = idx & 1023;
        int oc  = rem >> 6;
        int ic0 = rem & 63;
        u16 v[8];
#pragma unroll
        for (int j = 0; j < 8; ++j) {
            int ic = ic0 + j;
            float f = (ic < 50) ? pcw[(oc * 50 + ic) * 25 + tap] : 0.f;
            v[j] = f2bf(f);
        }
        *(short8*)&w_pc[idx] = *(short8*)v;
    } else if (blk == 539) {
        if (t < 128) {
            int n  = t >> 2;
            int k0 = (t & 3) * 8;
            u16 v[8];
#pragma unroll
            for (int j = 0; j < 8; ++j) {
                int k = k0 + j;
                float f = (n < 20 && k < 25) ? w1[n * 25 + k] : 0.f;
                v[j] = f2bf(f);
            }
            *(short8*)&w1t[t * 8] = *(short8*)v;
        }
    } else {
        for (int nn = t; nn < 512; nn += 256) {
            float bias = 0.f, wc0 = 0.f, wc1 = 0.f, f20 = 0.f, f21 = 0.f;
            if (nn < 500) {
                bias = f1b[nn];
                wc0  = fw[(size_t)nn * 3602 + 3600];
                wc1  = fw[(size_t)nn * 3602 + 3601];
                f20  = f2w[nn];
                f21  = f2w[502 + nn];
            }
            *(float4*)&wtab[nn * 8]     = make_float4(bias, wc0, wc1, f20);
            *(float4*)&wtab[nn * 8 + 4] = make_float4(f21, 0.f, 0.f, 0.f);
        }
    }
}

// ---------- Kernel 1: conv1+conv2 (MFMA) + pcaps (MFMA) + routing ----------
// (round-8 structure; im2col chunk swizzle col = k ^ ((row>>3)&3))
__global__ __launch_bounds__(256, 3) void k_convs(
    const float* __restrict__ x, const u16* __restrict__ w1t,
    const float* __restrict__ b1, const u16* __restrict__ w2t,
    const float* __restrict__ b2, const u16* __restrict__ w_pc,
    const float* __restrict__ pcb, const float* __restrict__ rw,
    u32* __restrict__ h_bf, float* __restrict__ cbuf)
{
    __shared__ __align__(16) u16 smem[24704];
    u16* h1t = smem;            // 17920 shorts
    u16* xbf = smem + 17920;    // 2304 shorts
    u16* im2 = smem + 20224;    // 4480 shorts ([112][40], chunk-swizzled)

    const int t = threadIdx.x;
    const int b = blockIdx.x;

    for (int i = t; i < 2688; i += 256) {
        int pos = i / 6, c = i - 6 * pos;
        ((u32*)h1t)[pos * 20 + 10 + c] = 0u;
    }
    const float* xb = x + b * 2160;
    for (int i = t; i < 2160; i += 256) {
        int r = i / 60, c = i - 60 * r;
        xbf[r * 64 + c] = f2bf(xb[i]);
    }
    __syncthreads();

    const int lane = t & 63, w = t >> 6;
    const int r16  = lane & 15;
    const int q    = lane >> 4;

    // ---- conv1 via MFMA, 16 chunks of 2 pre-pool rows (112 positions) ----
    short8 w1f[2];
#pragma unroll
    for (int nt = 0; nt < 2; ++nt)
        w1f[nt] = *(const short8*)&w1t[(nt * 16 + r16) * 32 + q * 8];

    const int p_   = t;               // builder position (t<112)
    const int px_  = p_ >> 2;
    const int dy_  = (p_ & 3) >> 1, dx_ = p_ & 1;
    const int xc_  = 2 * px_ + dx_;
    const int j0_  = xc_ >> 1;
    const int par_ = xc_ & 1;
    const int sw_  = (p_ >> 3) & 3;   // write-side chunk swizzle

#pragma unroll 1
    for (int c = 0; c < 16; ++c) {
        if (t < 112) {
            u16 tap[25];
#pragma unroll
            for (int r = 0; r < 5; ++r) {
                const u32* U = (const u32*)&xbf[(2 * c + dy_ + r) * 64];
                u32 A0 = U[j0_], A1 = U[j0_ + 1], A2 = U[j0_ + 2];
                u16 e0 = par_ ? (u16)(A0 >> 16) : (u16)A0;
                u16 e1 = par_ ? (u16)A1         : (u16)(A0 >> 16);
                u16 e2 = par_ ? (u16)(A1 >> 16) : (u16)A1;
                u16 e3 = par_ ? (u16)A2         : (u16)(A1 >> 16);
                u16 e4 = par_ ? (u16)(A2 >> 16) : (u16)A2;
                tap[r * 5 + 0] = e0; tap[r * 5 + 1] = e1; tap[r * 5 + 2] = e2;
                tap[r * 5 + 3] = e3; tap[r * 5 + 4] = e4;
            }
            u32 ow[16];
#pragma unroll
            for (int j = 0; j < 12; ++j)
                ow[j] = (u32)tap[2 * j] | ((u32)tap[2 * j + 1] << 16);
            ow[12] = (u32)tap[24];
            ow[13] = 0u; ow[14] = 0u; ow[15] = 0u;
            // chunk k (shorts 8k..8k+7) stored at column (k ^ sw_) -> per
            // 32-bit phase, lanes p and p+8/p+16 now hit different banks
            u32* dst = (u32*)&im2[p_ * 40];
            *(uint4*)&dst[(0 ^ sw_) * 4] = make_uint4(ow[0],  ow[1],  ow[2],  ow[3]);
            *(uint4*)&dst[(1 ^ sw_) * 4] = make_uint4(ow[4],  ow[5],  ow[6],  ow[7]);
            *(uint4*)&dst[(2 ^ sw_) * 4] = make_uint4(ow[8],  ow[9],  ow[10], ow[11]);
            *(uint4*)&dst[(3 ^ sw_) * 4] = make_uint4(ow[12], ow[13], ow[14], ow[15]);
        }
        __syncthreads();
#pragma unroll
        for (int mi = 0; mi < 2; ++mi) {
            int mt = w + 4 * mi;
            if (mt < 7) {
                int m  = mt * 16 + r16;
                int sr = (m >> 3) & 3;        // read-side swizzle
                short8 af = *(const short8*)&im2[m * 40 + ((q ^ sr) * 8)];
                floatx4 a1[2] = {};
#pragma unroll
                for (int nt = 0; nt < 2; ++nt)
                    a1[nt] = __builtin_amdgcn_mfma_f32_16x16x32_bf16(
                        af, w1f[nt], a1[nt], 0, 0, 0);
                int pq = mt * 4 + q;
#pragma unroll
                for (int nt = 0; nt < 2; ++nt) {
                    int oc = nt * 16 + r16;
                    if (oc < 20) {
                        floatx4 a = a1[nt];
                        float v = fmaxf(fmaxf(a[0], a[1]), fmaxf(a[2], a[3]))
                                + b1[oc];
                        h1t[(c * 28 + pq) * 40 + oc] = f2bf(v);
                    }
                }
            }
        }
        __syncthreads();
    }

    // ---- conv2 via MFMA: M=288 Z-ordered pre-pool, N=64, K=32, 25 taps ----
    int abase[5];
#pragma unroll
    for (int i = 0; i < 5; ++i) {
        int mt = w + 4 * i;
        if (mt < 18) {
            int m  = mt * 16 + r16;
            int pq = m >> 2, sub = m & 3;
            int py = pq / 12, px = pq - py * 12;
            int yy = py * 2 + (sub >> 1);
            int xx = px * 2 + (sub & 1);
            abase[i] = (yy * 28 + xx) * 40 + q * 8;
        } else abase[i] = 0;
    }
    floatx4 acc2[5][4] = {};
    const u16* wtb = w2t + r16 * 32 + q * 8;

    short8 bf[4];
#pragma unroll
    for (int nt = 0; nt < 4; ++nt)
        bf[nt] = *(const short8*)&wtb[nt * 512];

#pragma unroll 1
    for (int tap = 0; tap < 25; ++tap) {
        short8 bfn[4];
        if (tap < 24) {
#pragma unroll
            for (int nt = 0; nt < 4; ++nt)
                bfn[nt] = *(const short8*)&wtb[(tap + 1) * 2048 + nt * 512];
        }
        int r = tap / 5, s = tap - 5 * r;
        int aoff = r * 1120 + s * 40;
#pragma unroll
        for (int i = 0; i < 5; ++i) {
            int mt = w + 4 * i;
            if (mt < 18) {
                short8 af = *(const short8*)&h1t[abase[i] + aoff];
#pragma unroll
                for (int nt = 0; nt < 4; ++nt)
                    acc2[i][nt] = __builtin_amdgcn_mfma_f32_16x16x32_bf16(
                        af, bf[nt], acc2[i][nt], 0, 0, 0);
            }
        }
#pragma unroll
        for (int nt = 0; nt < 4; ++nt) bf[nt] = bfn[nt];
    }
    __syncthreads();

    // ---- pool -> hs2[pos*50+oc] f32 @smem[0]; zero hsbuf region ----
    float* hs2 = (float*)smem;
#pragma unroll
    for (int i = 0; i < 5; ++i) {
        int mt = w + 4 * i;
        if (mt < 18) {
            int pq = mt * 4 + q;
#pragma unroll
            for (int nt = 0; nt < 4; ++nt) {
                int oc = nt * 16 + r16;
                if (oc < 50) {
                    floatx4 a = acc2[i][nt];
                    hs2[pq * 50 + oc] =
                        fmaxf(fmaxf(a[0], a[1]), fmaxf(a[2], a[3])) + b2[oc];
                }
            }
        }
    }
    for (int i = t; i < 6336; i += 256)
        ((u32*)smem)[3600 + i] = 0u;
    __syncthreads();

    // ---- pack h_bf (stride 1856 u32) + fill hsbuf interior ----
    u16* hsbuf = smem + 7200;
    u32* ho = h_bf + (size_t)b * 1856;
    for (int i = t; i < 1856; i += 256) {
        if (i < 1800) {
            int k2 = 2 * i;
            u32 pk = (u32)f2bf(hs2[k2]) | ((u32)f2bf(hs2[k2 + 1]) << 16);
            ho[i] = pk;
            int pos = k2 / 50;
            int oc  = k2 - 50 * pos;
            int ph  = pos / 12, pw = pos - 12 * ph;
            ((u32*)hsbuf)[((((ph + 2) * 16) + pw + 2) * 72 + oc) >> 1] = pk;
        } else ho[i] = 0u;
    }
    __syncthreads();

    // ---- pcaps via MFMA ----
    int pbase[5];
#pragma unroll
    for (int mt = 0; mt < 5; ++mt) {
        int m  = mt * 16 + r16;
        int ph = m / 12, pw = m - 12 * ph;
        pbase[mt] = (ph * 16 + pw) * 72 + q * 8;
    }
    floatx4 pacc[5] = {};
    const u16* wp = w_pc + r16 * 64 + q * 8;
    const int ntap = (28 - w) >> 2;
#pragma unroll 1
    for (int tt = 0; tt < ntap; ++tt) {
        int tap = w + 4 * tt;
        short8 b0 = *(const short8*)&wp[tap * 1024];
        short8 b1 = *(const short8*)&wp[tap * 1024 + 32];
        int r = tap / 5, s = tap - 5 * r;
        int aoff = (r * 16 + s) * 72;
#pragma unroll
        for (int mt = 0; mt < 5; ++mt) {
            short8 a0 = *(const short8*)&hsbuf[pbase[mt] + aoff];
            short8 a1 = *(const short8*)&hsbuf[pbase[mt] + aoff + 32];
            pacc[mt] = __builtin_amdgcn_mfma_f32_16x16x32_bf16(a0, b0, pacc[mt], 0, 0, 0);
            pacc[mt] = __builtin_amdgcn_mfma_f32_16x16x32_bf16(a1, b1, pacc[mt], 0, 0, 0);
        }
    }
    __syncthreads();

    float* psum = (float*)(smem + 7200);  // [4][80*17] f32
#pragma unroll
    for (int mt = 0; mt < 5; ++mt)
#pragma unroll
        for (int i = 0; i < 4; ++i) {
            int m = mt * 16 + q * 4 + i;
            psum[w * 1360 + m * 17 + r16] = pacc[mt][i];
        }
    __syncthreads();

    for (int i = t; i < 1152; i += 256) {
        int m = i >> 4, oc = i & 15;
        int a = m * 17 + oc;
        float s = psum[a] + psum[1360 + a] + psum[2720 + a] + psum[4080 + a]
                + pcb[oc];
        psum[a] = s;
    }
    __syncthreads();

    float* pri = (float*)(smem + 19872);
    for (int r = t; r < 288; r += 256) {
        int sub = r / 72;
        int pos = r - sub * 72;
        float u0 = psum[pos * 17 + 0  + sub];
        float u1 = psum[pos * 17 + 4  + sub];
        float u2 = psum[pos * 17 + 8  + sub];
        float u3 = psum[pos * 17 + 12 + sub];
        float n2 = u0 * u0 + u1 * u1 + u2 * u2 + u3 * u3;
        float scale = (n2 / (1.0f + n2)) * rsqrtf(n2);
        u0 *= scale; u1 *= scale; u2 *= scale; u3 *= scale;
#pragma unroll
        for (int k = 0; k < 2; ++k) {
            const float4 wv = *(const float4*)&rw[(k * 288 + r) * 4];
            pri[k * 288 + r] = u0 * wv.x + u1 * wv.y + u2 * wv.z + u3 * wv.w;
        }
    }
    __syncthreads();

    if (w < 2) {
        const float* pr = &pri[w * 288];
        float p[5];
        bool  val[5];
#pragma unroll
        for (int j = 0; j < 5; ++j) {
            int r  = j * 64 + lane;
            val[j] = r < 288;
            p[j]   = val[j] ? pr[r] : 0.0f;
        }
        float tot = wave_sum(p[0] + p[1] + p[2] + p[3] + p[4]);
        float s = tot * (1.0f / 288.0f);
        float a = s * fabsf(s) / (1.0f + s * s);
#pragma unroll
        for (int it = 0; it < 2; ++it) {
            float l[5];
            float lm = -INFINITY;
#pragma unroll
            for (int j = 0; j < 5; ++j) {
                l[j] = val[j] ? p[j] * a : -INFINITY;
                lm   = fmaxf(lm, l[j]);
            }
            lm = wave_max(lm);
            float se = 0.f, sp = 0.f;
#pragma unroll
            for (int j = 0; j < 5; ++j) {
                float e = val[j] ? expf(l[j] - lm) : 0.f;
                se += e;
                sp += e * p[j];
            }
            se = wave_sum(se);
            sp = wave_sum(sp);
            float sv = sp / se;
            float v  = sv * fabsf(sv) / (1.0f + sv * sv);
            if (it == 0) a += v;
            else if (lane == 0) cbuf[b * 2 + w] = v;
        }
    }
}

// ---------- Kernel 2: fc1 partial GEMM, m97-style async staging ------------
// grid (16, 8, 4): 128m x 64n tile, k-split s covers K range [s*928,(s+1)*928)
__global__ __launch_bounds__(256) void k_fc1(
    const u16* __restrict__ h_bf, const u16* __restrict__ w_bf,
    float* __restrict__ f1buf)
{
    __shared__ __align__(16) u16 As[128 * 32];   // 8192 B
    __shared__ __align__(16) u16 Bs[64 * 32];    // 4096 B
    const int t = threadIdx.x;
    const int lane = t & 63, w = t >> 6;
    const int m0 = blockIdx.x * 128;
    const int n0 = blockIdx.y * 64;
    const int s  = blockIdx.z;
    const int k0 = s * 928;

    const int ai0 = (w * 2) * 64 + lane;
    const int ai1 = (w * 2 + 1) * 64 + lane;
    const int bi  = w * 64 + lane;
    const u16* ga0 = h_bf + (size_t)(m0 + (ai0 >> 2)) * KP + k0 + (ai0 & 3) * 8;
    const u16* ga1 = h_bf + (size_t)(m0 + (ai1 >> 2)) * KP + k0 + (ai1 & 3) * 8;
    const u16* gb  = w_bf + (size_t)(n0 + (bi  >> 2)) * KP + k0 + (bi  & 3) * 8;
    u16* lA0 = As + (w * 2) * 512;
    u16* lA1 = As + (w * 2 + 1) * 512;
    u16* lB  = Bs + w * 512;

    const int r16 = lane & 15, q = lane >> 4;
    const int ar = (w * 32 + r16) * 32 + q * 8;
    const int br = r16 * 32 + q * 8;

    floatx4 acc[2][4] = {};
#pragma unroll 1
    for (int it = 0; it < 29; ++it) {
        const int ko = it * 32;
        GLD(ga0 + ko, lA0);
        GLD(ga1 + ko, lA1);
        GLD(gb + ko, lB);
        __syncthreads();
        short8 af0 = *(const short8*)&As[ar];
        short8 af1 = *(const short8*)&As[ar + 512];
#pragma unroll
        for (int nt = 0; nt < 4; ++nt) {
            short8 bfv = *(const short8*)&Bs[br + nt * 512];
            acc[0][nt] = __builtin_amdgcn_mfma_f32_16x16x32_bf16(af0, bfv, acc[0][nt], 0, 0, 0);
            acc[1][nt] = __builtin_amdgcn_mfma_f32_16x16x32_bf16(af1, bfv, acc[1][nt], 0, 0, 0);
        }
        __syncthreads();
    }

    float* fo = f1buf + (size_t)s * (2048 * 512);
    const int mb = m0 + w * 32;
#pragma unroll
    for (int mt2 = 0; mt2 < 2; ++mt2)
#pragma unroll
        for (int nt = 0; nt < 4; ++nt) {
            int n = n0 + nt * 16 + r16;
#pragma unroll
            for (int i = 0; i < 4; ++i) {
                int m = mb + mt2 * 16 + q * 4 + i;
                fo[(size_t)m * 512 + n] = acc[mt2][nt][i];
            }
        }
}

// ---------- Kernel 3: fc2 final — sum partials, relu, dot ------------------
__global__ __launch_bounds__(256) void k_fc2(
    const float* __restrict__ f1buf, const float* __restrict__ wtab,
    const float* __restrict__ cc, const float* __restrict__ y,
    const float* __restrict__ f2w, const float* __restrict__ f2b,
    float* __restrict__ out)
{
    const int b = blockIdx.x * 4 + (threadIdx.x >> 6);
    const int lane = threadIdx.x & 63;
    const float* fb = f1buf + (size_t)b * 512;
    const float c0 = cc[b * 2], c1 = cc[b * 2 + 1];
    float s0 = 0.f, s1 = 0.f;
#pragma unroll
    for (int j = 0; j < 8; ++j) {
        int n = lane + j * 64;
        float raw = fb[n] + fb[1048576 + n] + fb[2097152 + n] + fb[3145728 + n];
        float4 t0 = *(const float4*)&wtab[n * 8];
        float  f21 = wtab[n * 8 + 4];
        float v = fmaxf(raw + t0.x + c0 * t0.y + c1 * t0.z, 0.f);
        s0 += v * t0.w;
        s1 += v * f21;
    }
    s0 = wave_sum(s0);
    s1 = wave_sum(s1);
    if (lane == 0) {
        float y0 = y[b * 2], y1 = y[b * 2 + 1];
        out[b * 2]     = s0 + f2b[0] + y0 * f2w[500] + y1 * f2w[501];
        out[b * 2 + 1] = s1 + f2b[1] + y0 * f2w[1002] + y1 * f2w[1003];
    }
}

// ---------------------------------------------------------------------------
extern "C" void kernel_launch(void* const* d_in, const int* in_sizes, int n_in,
                              void* d_out, int out_size, void* d_ws, size_t ws_size,
                              hipStream_t stream) {
    const float* x    = (const float*)d_in[0];
    const float* y    = (const float*)d_in[1];
    const float* c1w  = (const float*)d_in[2];
    const float* c1b  = (const float*)d_in[3];
    const float* c2w  = (const float*)d_in[4];
    const float* c2b  = (const float*)d_in[5];
    const float* pcw  = (const float*)d_in[6];
    const float* pcb  = (const float*)d_in[7];
    const float* rw   = (const float*)d_in[8];
    const float* f1w  = (const float*)d_in[9];
    const float* f1b  = (const float*)d_in[10];
    const float* f2w  = (const float*)d_in[11];
    const float* f2b  = (const float*)d_in[12];
    float* out = (float*)d_out;

    // workspace layout (~36 MB)
    u32*   h_bf  = (u32*)d_ws;                            // 2048*1856 u32
    u16*   w_bf  = (u16*)(h_bf + (size_t)BATCH * 1856);   // 512*3712 u16
    u16*   w2t   = w_bf + (size_t)512 * KP;               // 25*64*32 u16
    u16*   w_pc  = w2t + 51200;                           // 25*16*64 u16
    u16*   w1t   = w_pc + 25600;                          // 32*32 u16
    float* cbuf  = (float*)(w1t + 1024);                  // 4096 f32
    float* wtab  = cbuf + 4096;                           // 4096 f32
    float* f1buf = wtab + 4096;                           // 4*2048*512 f32

    k_prep<<<541, 256, 0, stream>>>(f1w, w_bf, c2w, w2t, pcw, w_pc, c1w, w1t,
                                    f1b, f2w, wtab);
    k_convs<<<BATCH, 256, 0, stream>>>(x, w1t, c1b, w2t, c2b, w_pc, pcb, rw,
                                       h_bf, cbuf);
    dim3 g4(16, 8, 4);
    k_fc1<<<g4, 256, 0, stream>>>((const u16*)h_bf, w_bf, f1buf);
    k_fc2<<<BATCH / 4, 256, 0, stream>>>(f1buf, wtab, cbuf, y, f2w, f2b, out);
}